// Round 8
// baseline (112.180 us; speedup 1.0000x reference)
//
#include <hip/hip_runtime.h>

typedef short v8s __attribute__((ext_vector_type(8)));
typedef float v4f __attribute__((ext_vector_type(4)));
typedef float v16f __attribute__((ext_vector_type(16)));

// RNE float -> bf16 (matches float_quantize(exp=8, man=7) for these inputs).
__device__ __forceinline__ unsigned short rne_bf16(float f) {
  unsigned u = __float_as_uint(f);
  return (unsigned short)((u + 0x7fffu + ((u >> 16) & 1u)) >> 16);
}
__device__ __forceinline__ float qbf(float f) {
  return __uint_as_float(((unsigned)rne_bf16(f)) << 16);
}

__device__ __forceinline__ void gload_lds16(const void* g, void* l) {
  __builtin_amdgcn_global_load_lds((__attribute__((address_space(1))) void*)g,
                                   (__attribute__((address_space(3))) void*)l,
                                   16, 0, 0);
}

#define PCS 72  // prep LDS col stride (shorts)

// ---------------------------------------------------------------------------
// prep: blocks 0..1791 = (b,h): quantize+transpose x -> Xp[b][h+1][col][slot],
//   58x58 rows/cols with borders zeroed, slot = c8 ^ (col & 7).
// The XOR pre-swizzle (T2/m173, rule #21) means conv's LINEAR global_load_lds
// staging lands a bank-conflict-benign tile; conv reads with the same XOR.
// Blocks 1792..1823: weights -> fragment-major Wt2 (unchanged layout):
//   Wt2[((pos*4+kk)*4+g)*512 + lane*8 + (c&7)], lane=(n&31)+32*((c>>3)&1).
// ---------------------------------------------------------------------------
__global__ __launch_bounds__(256) void prep(const float* __restrict__ x,
                                            const float* __restrict__ w,
                                            unsigned short* __restrict__ Xp,
                                            unsigned short* __restrict__ Wt2) {
  const int blk = blockIdx.x;
  const int tid = threadIdx.x;

  if (blk >= 1792) {  // ---- weight reorder ----
    int t = (blk - 1792) * 256 + tid;  // 0..8191 = n*64 + c
    int n = t >> 6, c = t & 63;
    int kk = c >> 4;
    int lane = (n & 31) + 32 * ((c >> 3) & 1);
    const float* src = w + (size_t)t * 9;
#pragma unroll
    for (int pos = 0; pos < 9; ++pos) {
      int idx = (((pos * 4 + kk) * 4 + (n >> 5)) << 9) + lane * 8 + (c & 7);
      Wt2[idx] = rne_bf16(src[pos]);
    }
    return;
  }

  const int b = blk / 56, h = blk % 56;
  __shared__ __align__(16) unsigned short tile[56 * PCS];  // [w][c]

  // zero pad borders (ws is re-poisoned before every launch)
  unsigned short* rowp = Xp + (((size_t)b * 58 + (h + 1)) * 58) * 64;
  if (tid < 64) { rowp[tid] = 0; rowp[57 * 64 + tid] = 0; }
  if (h == 0) {
    unsigned short* r0 = Xp + ((size_t)b * 58 * 58) * 64;
    unsigned short* r57 = r0 + (size_t)57 * 58 * 64;
    for (int i = tid; i < 58 * 64; i += 256) { r0[i] = 0; r57[i] = 0; }
  }

  // phase 1: 448 slots = 8 chan-octets * 56 w; reads coalesced along w
#pragma unroll
  for (int it = 0; it < 2; ++it) {
    int i = it * 256 + tid;
    if (i < 448) {
      int c8 = i / 56, ww = i - c8 * 56;
      const float* xb = x + ((size_t)(b * 64 + c8 * 8)) * 3136 + h * 56 + ww;
      v8s pk;
#pragma unroll
      for (int j = 0; j < 8; ++j) pk[j] = (short)rne_bf16(xb[(size_t)j * 3136]);
      *(v8s*)&tile[ww * PCS + c8 * 8] = pk;
    }
  }
  __syncthreads();

  // phase 2: interior write, XOR-swizzled slot, 128 B contiguous per w
  unsigned short* dst = Xp + (((size_t)b * 58 + (h + 1)) * 58 + 1) * 64;
#pragma unroll
  for (int it = 0; it < 2; ++it) {
    int i = it * 256 + tid;
    if (i < 448) {
      int ww = i >> 3, cb = i & 7;
      int slot = cb ^ ((ww + 1) & 7);  // col = ww+1 in padded coords
      *(v8s*)&dst[ww * 64 + slot * 8] = *(const v8s*)&tile[ww * PCS + cb * 8];
    }
  }
}

// ---------------------------------------------------------------------------
// conv, round 8: async global_load_lds staging (unsinkable, zero-VGPR),
// no quantize/branches in the chain.  R5 evidence: register prefetch gets
// sunk by regalloc (VGPR=128 can't hold pf) -> pure-HIP reg prefetch dead.
// Grid 896 (2-row x 128-ch tiles), XCD-swizzled (each XCD: 4 batches whose
// 1.7MB Xp slice is L2-resident).  Per block:
//   8x global_load_lds_dwordx4 (4 contiguous Xp rows = 29696 B, linear LDS)
//   -> ONE barrier -> ladder (reads with matching XOR) -> direct stores.
// LDS 30 KB; no f-regs -> VGPR ~115; launch_bounds(256,3) = 12 waves/CU.
// Accumulation order per output chain identical to the verified kernel.
// ---------------------------------------------------------------------------
__global__ __launch_bounds__(256, 3) void conv(const unsigned short* __restrict__ Xp,
                                               const unsigned short* __restrict__ Wt2,
                                               const float* __restrict__ bias,
                                               float* __restrict__ out) {
  __shared__ __align__(16) char smem[29696 + 512];
  unsigned short* xs = (unsigned short*)smem;   // [4 rows][58 cols][64 c] swz
  float* qb = (float*)(smem + 29696);           // 128 quantized biases

  // bijective XCD swizzle: 896 = 8 * 112; each XCD gets 4 whole batches
  const int id = blockIdx.x;
  const int orig = (id & 7) * 112 + (id >> 3);
  const int pair = orig % 28, b = orig / 28;
  const int oh0 = pair * 2;
  const int tid = threadIdx.x;
  const int wv = tid >> 6, lane = tid & 63;
  const int lj = lane & 31, lh = lane >> 5;
  const int lj1 = 28 + (lj < 27 ? lj : 27);  // sp-tile1 col offset (clamped)
  const int rw = wv & 1;                     // wave's output row within pair
  const int gg2 = (wv >> 1) * 2;             // wave's first 32-ch group

  // ---- async staging: tile = padded rows oh0..oh0+3, contiguous in Xp ----
  const char* src = (const char*)Xp + ((size_t)b * 58 + oh0) * 7424;
  char* lb = (char*)smem;
#pragma unroll
  for (int it = 0; it < 7; ++it)
    gload_lds16(src + it * 4096 + tid * 16, lb + it * 4096 + wv * 1024);
  if (tid < 64) gload_lds16(src + 28672 + tid * 16, lb + 28672);

  if (tid < 128) qb[tid] = qbf(bias[tid]);

  // ---- W fragments pos0; half-pos double buffer ----
  const unsigned short* wt0 = Wt2 + lane * 8;
  v8s wa[4], wb[4];
#define WLOADH(POS, HALF, BUF)                                                 \
  {                                                                            \
    _Pragma("unroll") for (int kk2 = 0; kk2 < 2; ++kk2) {                      \
      _Pragma("unroll") for (int gi = 0; gi < 2; ++gi) {                       \
        BUF[kk2 * 2 + gi] = *(const v8s*)(                                     \
            wt0 + ((((POS)*4 + (HALF)*2 + kk2) * 4 + gg2 + gi) << 9));         \
      }                                                                        \
    }                                                                          \
  }
  WLOADH(0, 0, wa);
  WLOADH(0, 1, wb);

  __syncthreads();  // the ONLY barrier: drains our gload_lds (needed anyway)

  v16f acc[2][2];  // [n-group][sp tile]
#pragma unroll
  for (int a = 0; a < 2; ++a)
#pragma unroll
    for (int s = 0; s < 2; ++s)
#pragma unroll
      for (int e = 0; e < 16; ++e) acc[a][s][e] = 0.0f;

  // read-side XOR matches prep's pre-swizzle: byte = row*7424? no — within
  // tile: (row*58+col)*128 + ((c8 ^ (col&7))<<4), c8 = lh + kk2*2 + half*4
#define COMPH(POS, HALF, BUF)                                                  \
  {                                                                            \
    const int kh = (POS) / 3, kw = (POS) % 3;                                  \
    const int col0 = kw + lj, col1 = kw + lj1;                                 \
    const char* rbase = (const char*)xs + ((rw + kh) * 58) * 128;              \
    _Pragma("unroll") for (int kk2 = 0; kk2 < 2; ++kk2) {                      \
      const int c8f = lh + kk2 * 2 + (HALF)*4;                                 \
      v8s q0 = *(const v8s*)(rbase + col0 * 128 + ((c8f ^ (col0 & 7)) << 4));  \
      v8s q1 = *(const v8s*)(rbase + col1 * 128 + ((c8f ^ (col1 & 7)) << 4));  \
      _Pragma("unroll") for (int gi = 0; gi < 2; ++gi) {                       \
        acc[gi][0] = __builtin_amdgcn_mfma_f32_32x32x16_bf16(BUF[kk2 * 2 + gi], q0, acc[gi][0], 0, 0, 0); \
        acc[gi][1] = __builtin_amdgcn_mfma_f32_32x32x16_bf16(BUF[kk2 * 2 + gi], q1, acc[gi][1], 0, 0, 0); \
      }                                                                        \
    }                                                                          \
  }

  COMPH(0, 0, wa); WLOADH(1, 0, wa); COMPH(0, 1, wb); WLOADH(1, 1, wb);
  COMPH(1, 0, wa); WLOADH(2, 0, wa); COMPH(1, 1, wb); WLOADH(2, 1, wb);
  COMPH(2, 0, wa); WLOADH(3, 0, wa); COMPH(2, 1, wb); WLOADH(3, 1, wb);
  COMPH(3, 0, wa); WLOADH(4, 0, wa); COMPH(3, 1, wb); WLOADH(4, 1, wb);
  COMPH(4, 0, wa); WLOADH(5, 0, wa); COMPH(4, 1, wb); WLOADH(5, 1, wb);
  COMPH(5, 0, wa); WLOADH(6, 0, wa); COMPH(5, 1, wb); WLOADH(6, 1, wb);
  COMPH(6, 0, wa); WLOADH(7, 0, wa); COMPH(6, 1, wb); WLOADH(7, 1, wb);
  COMPH(7, 0, wa); WLOADH(8, 0, wa); COMPH(7, 1, wb); WLOADH(8, 1, wb);
  COMPH(8, 0, wa); COMPH(8, 1, wb);

  // ---- direct fire-and-forget stores from acc (no barrier, no LDS) ----
  // ch = gg2*32 + gi*32 + (e&3)+8*(e>>2) + 4*lh  (C/D layout, verified)
  if (lj < 28) {
    float* ob = out + ((size_t)(b * 128 + gg2 * 32 + 4 * lh)) * 3136 +
                (size_t)(oh0 + rw) * 56 + lj;
#pragma unroll
    for (int gi = 0; gi < 2; ++gi) {
#pragma unroll
      for (int e = 0; e < 16; ++e) {
        const int chp = (e & 3) + 8 * (e >> 2);
        float bb = qb[gg2 * 32 + gi * 32 + chp + 4 * lh];
        float* d = ob + (size_t)(gi * 32 + chp) * 3136;
        d[0] = acc[gi][0][e] + bb;
        d[28] = acc[gi][1][e] + bb;
      }
    }
  }
}

extern "C" void kernel_launch(void* const* d_in, const int* in_sizes, int n_in,
                              void* d_out, int out_size, void* d_ws, size_t ws_size,
                              hipStream_t stream) {
  const float* x = (const float*)d_in[0];     // [32,64,56,56]
  const float* w = (const float*)d_in[1];     // [128,64,3,3]
  const float* bias = (const float*)d_in[2];  // [128]
  float* out = (float*)d_out;                 // [32,128,56,56] fp32

  unsigned short* Xp = (unsigned short*)d_ws;              // 32*58*58*64 bf16
  const size_t XP_BYTES = (size_t)32 * 58 * 58 * 64 * 2;   // 13,778,944 B
  unsigned short* Wt2 = (unsigned short*)((char*)d_ws + XP_BYTES);  // 147 KB

  prep<<<1792 + 32, 256, 0, stream>>>(x, w, Xp, Wt2);
  conv<<<896, 256, 0, stream>>>(Xp, Wt2, bias, out);
}